// Round 5
// baseline (160.797 us; speedup 1.0000x reference)
//
#include <hip/hip_runtime.h>
#include <stdint.h>

// ---------------------------------------------------------------------------
// WideAndDeep: B=16384, F=3, C=256, D=64, H=1024, ND=13
// R19: (a) gemm2 epilogue reduces wn-wave partials in (dead) GEMM LDS ->
// 1 atomicAdd per row per block (4x fewer device atomics); (b) sigmoid
// fused into gemm2 via per-row-strip counter: 4th-arriving block (of the 4
// bx sharers) reads finished logits with atomic reads (same coherent point
// as the atomic writes -- no fences, no R8/R14 storm risk) and stores
// sigmoid. Counters zeroed by prep. GEMM main loops byte-identical to R18
// (159.1us): R16 uniform 8-phase schedule, emb-gather A-staging for gemm1.
// 8-phase stage order per iter:
//   p1:A.O.h0  p2:A.O.h1  p3:B.E.h0  p4:B.E.h1[vmcnt4]
//   p5:A.E.h0  p6:A.E.h1  p7:B.O.h0  p8:B.O.h1[vmcnt4]
// FIFO: vmcnt(4)@p4 retires {B.O prev, A.O}; vmcnt(4)@p8 retires {B.E,A.E}.
// Wrap loads (last iter) re-read tile 0 (cache-absorbed) to keep pacing
// uniform (R17 proved tail peeling regresses).
// ---------------------------------------------------------------------------

#define BATCH 16384
#define HDIM 1024
#define K1 256
#define DEEP_IN 205

typedef short bf16x8 __attribute__((ext_vector_type(8)));
typedef float f32x4 __attribute__((ext_vector_type(4)));
typedef uint16_t u16x8 __attribute__((ext_vector_type(8)));
typedef uint16_t u16x4 __attribute__((ext_vector_type(4)));

__device__ __forceinline__ uint16_t f2bf(float f) {
    uint32_t x;
    __builtin_memcpy(&x, &f, 4);
    uint32_t r = (x + 0x7fffu + ((x >> 16) & 1u)) >> 16;
    return (uint16_t)r;
}

__device__ __forceinline__ void async_ld16(const uint16_t* g, uint16_t* l) {
    __builtin_amdgcn_global_load_lds(
        (const __attribute__((address_space(1))) uint32_t*)g,
        (__attribute__((address_space(3))) uint32_t*)l, 16, 0, 0);
}

// ---------------------------------------------------------------------------
// prep: everything the GEMMs need, one elementwise kernel.
//   [0, 24)      : emb -> emb_bf16 (49152 elems, x8)
//   [24, 536)    : dtail [B][64] bf16: cols 0..12 = dense, 13..63 = 0 (x8)
//   [536, 664)   : W1 -> bf16, 205 -> 256 K-pad (x8)
//   [664, 1176)  : W2 -> bf16 (x8)
//   [1176, 1240) : wide path (sparse gathers + dense dot) + b3 seed
//   [1240]       : zero the 64 row-strip completion counters
// ---------------------------------------------------------------------------
__global__ __launch_bounds__(256) void prep_kernel(
    const int* __restrict__ sp, const float* __restrict__ dense,
    const float* __restrict__ emb, const float* __restrict__ W1,
    const float* __restrict__ W2, const float* __restrict__ ww,
    const float* __restrict__ wb, const float* __restrict__ b3,
    uint16_t* __restrict__ embb, uint16_t* __restrict__ dtail,
    uint16_t* __restrict__ W1b, uint16_t* __restrict__ W2b,
    float* __restrict__ wide, int* __restrict__ cnt)
{
    const int bid = blockIdx.x;
    const int tid = threadIdx.x;
    if (bid < 24) {                        // ---- emb -> bf16 (3*256*64 = 49152)
        int k = bid * 256 + tid;           // < 6144 vec8
        const float* src = emb + (size_t)k * 8;
        float4 v0 = *(const float4*)src;
        float4 v1 = *(const float4*)(src + 4);
        u16x8 o;
        o[0] = f2bf(v0.x); o[1] = f2bf(v0.y); o[2] = f2bf(v0.z); o[3] = f2bf(v0.w);
        o[4] = f2bf(v1.x); o[5] = f2bf(v1.y); o[6] = f2bf(v1.z); o[7] = f2bf(v1.w);
        *(u16x8*)(embb + (size_t)k * 8) = o;
    } else if (bid < 536) {                // ---- dense tail [16384][64]
        int idx = (bid - 24) * 256 + tid;  // < 131072 vec8
        int b = idx >> 3, c0 = (idx & 7) * 8;
        u16x8 o;
#pragma unroll
        for (int t = 0; t < 8; t++) {
            int c = c0 + t;
            o[t] = (c < 13) ? f2bf(dense[b * 13 + c]) : (uint16_t)0;
        }
        *(u16x8*)(dtail + (size_t)b * 64 + c0) = o;
    } else if (bid < 664) {                // ---- W1 convert, 205 -> 256
        int idx = (bid - 536) * 256 + tid;     // < 32768
        int n = idx >> 5, c0 = (idx & 31) * 8;
        u16x8 o;
#pragma unroll
        for (int t = 0; t < 8; t++) {
            int c = c0 + t;
            o[t] = (c < DEEP_IN) ? f2bf(W1[n * DEEP_IN + c]) : (uint16_t)0;
        }
        *(u16x8*)(W1b + (size_t)n * K1 + c0) = o;
    } else if (bid < 1176) {               // ---- W2 convert (x8)
        int k = (bid - 664) * 256 + tid;       // < 131072
        const float* src = W2 + (size_t)k * 8;
        float4 v0 = *(const float4*)src;
        float4 v1 = *(const float4*)(src + 4);
        u16x8 o;
        o[0] = f2bf(v0.x); o[1] = f2bf(v0.y); o[2] = f2bf(v0.z); o[3] = f2bf(v0.w);
        o[4] = f2bf(v1.x); o[5] = f2bf(v1.y); o[6] = f2bf(v1.z); o[7] = f2bf(v1.w);
        *(u16x8*)(W2b + (size_t)k * 8) = o;
    } else if (bid < 1240) {               // ---- wide path (+ b3 seed)
        int b = (bid - 1176) * 256 + tid;      // < 16384
        int s0 = sp[b * 3], s1 = sp[b * 3 + 1], s2 = sp[b * 3 + 2];
        float w = wb[0] + b3[0];
        w += ww[s0] + ww[256 + s1] + ww[512 + s2];
        w += ww[768    + s0 * 3 + s1];
        w += ww[66304  + s0 * 3 + s2];
        w += ww[131840 + s1 * 3 + s2];
        w += ww[197376 + (s0 * 3 + s1) * 3 + s2];
        const float* wd = ww + 16974592;
        float acc2 = 0.f;
#pragma unroll
        for (int j = 0; j < 13; j++) acc2 += dense[b * 13 + j] * wd[j];
        wide[b] = w + acc2;
    } else {                               // ---- zero completion counters
        if (tid < 64) cnt[tid] = 0;
    }
}

// ---------------------------------------------------------------------------
// Shared 8-phase GEMM core. 256x256 tile, 8 waves 2m x 4n, wave tile 128x64,
// BK=64, 128 KiB LDS (2 K-tile dbuf). LDS element map: AE=0 AO=16384
// BE=32768 BO=49152; each region [2 halves][128 rows][64 cols], row r's
// column bytes XOR-swizzled by (r&7)<<4 (inverse-swizzled global source,
// linear global_load_lds dest). Raw s_barrier; vmcnt(4) only at p4 & p8.
// Per-kernel STG8A/STG8B macros supply the staging source addresses.
// ---------------------------------------------------------------------------
#define BAR8() do { asm volatile("" ::: "memory");                             \
    __builtin_amdgcn_s_barrier();                                              \
    asm volatile("" ::: "memory"); } while (0)
#define VM4() asm volatile("s_waitcnt vmcnt(4)" ::: "memory")
#define VM0() asm volatile("s_waitcnt vmcnt(0)" ::: "memory")

#define LDA8(base, msub) do {                                                  \
    _Pragma("unroll") for (int mt = 0; mt < 4; mt++) {                         \
        int ro_ = (base) + ((msub) * 64 + mt * 16) * 64;                       \
        af[mt][0] = *(const bf16x8*)&lds[ro_ + kc0];                           \
        af[mt][1] = *(const bf16x8*)&lds[ro_ + kc1];                           \
    } } while (0)

#define LDB8(dst, base, nsub) do {                                             \
    _Pragma("unroll") for (int nt = 0; nt < 2; nt++) {                         \
        int ro_ = (base) + ((nsub) * 32 + nt * 16) * 64;                       \
        dst[nt][0] = *(const bf16x8*)&lds[ro_ + kc0];                          \
        dst[nt][1] = *(const bf16x8*)&lds[ro_ + kc1];                          \
    } } while (0)

#define MM8(msub, nsub, BF) do {                                               \
    __builtin_amdgcn_s_setprio(1);                                             \
    _Pragma("unroll") for (int mt = 0; mt < 4; mt++)                           \
    _Pragma("unroll") for (int nt = 0; nt < 2; nt++) {                         \
        acc[(msub)*4+mt][(nsub)*2+nt] = __builtin_amdgcn_mfma_f32_16x16x32_bf16( \
            af[mt][0], BF[nt][0], acc[(msub)*4+mt][(nsub)*2+nt], 0, 0, 0);     \
        acc[(msub)*4+mt][(nsub)*2+nt] = __builtin_amdgcn_mfma_f32_16x16x32_bf16( \
            af[mt][1], BF[nt][1], acc[(msub)*4+mt][(nsub)*2+nt], 0, 0, 0);     \
    }                                                                          \
    __builtin_amdgcn_s_setprio(0); } while (0)

#define GEMM8_DECLS()                                                          \
    const int tid = threadIdx.x;                                               \
    const int lane = tid & 63, wave = tid >> 6;                                \
    const int wm = wave >> 2, wn = wave & 3;                                   \
    const int id = blockIdx.x;                                                 \
    const int wg = (id & 7) * 32 + (id >> 3);                                  \
    const int by = wg >> 2, bx = wg & 3;                                       \
    const int bm = by * 256, bn = bx * 256;                                    \
    const int lam = lane & 15, lad = lane >> 4;                                \
    const int sw = (lane & 7) << 4;                                            \
    const int kc0 = ((lad * 16) ^ sw) >> 1;                                    \
    const int kc1 = ((64 + lad * 16) ^ sw) >> 1;                               \
    const int aBE = wm * 8192 + lam * 64;                                      \
    const int aBO = aBE + 16384;                                               \
    const int bBE = 32768 + (wn >> 1) * 8192 + ((wn & 1) * 64 + lam) * 64;     \
    const int bBO = bBE + 16384;                                               \
    const int trow = tid >> 3;                                                 \
    const int csel = ((tid & 7) ^ (trow & 7)) << 3;

// R16 main loop: uniform 8-phase schedule, wrap dead-loads keep pacing.
#define GEMM8_MAIN()                                                           \
    f32x4 acc[8][4];                                                           \
    _Pragma("unroll") for (int i = 0; i < 8; i++)                              \
        _Pragma("unroll") for (int j = 0; j < 4; j++) acc[i][j] = (f32x4)0.f;  \
    bf16x8 af[4][2], bf0[2][2], bf1[2][2];                                     \
    const int NT = K >> 6;                                                     \
    const int NI = K >> 7;                                                     \
    STG8A(0, 0, 0);     STG8A(0, 1, 0);                                        \
    STG8B(32768, 0, 0); STG8B(32768, 1, 0);                                    \
    STG8B(49152, 0, 64); STG8B(49152, 1, 64);                                  \
    VM4();                                                                     \
    BAR8();                                                                    \
    for (int it = 0; it < NI; ++it) {                                          \
        const int k1 = (2 * it + 1) * 64;                                      \
        const int t2 = 2 * it + 2, t3 = 2 * it + 3;                            \
        const int k2 = (t2 < NT ? t2 : 0) * 64;                                \
        const int k3 = (t3 < NT ? t3 : 0) * 64;                                \
        LDA8(aBE, 0); LDB8(bf0, bBE, 0); STG8A(16384, 0, k1);                  \
        BAR8(); MM8(0, 0, bf0); BAR8();                                        \
        LDB8(bf1, bBE, 1); STG8A(16384, 1, k1);                                \
        BAR8(); MM8(0, 1, bf1); BAR8();                                        \
        LDA8(aBE, 1); STG8B(32768, 0, k2);                                     \
        BAR8(); MM8(1, 1, bf1); BAR8();                                        \
        STG8B(32768, 1, k2);                                                   \
        BAR8(); MM8(1, 0, bf0); VM4(); BAR8();                                 \
        LDA8(aBO, 0); LDB8(bf0, bBO, 0); STG8A(0, 0, k2);                      \
        BAR8(); MM8(0, 0, bf0); BAR8();                                        \
        LDB8(bf1, bBO, 1); STG8A(0, 1, k2);                                    \
        BAR8(); MM8(0, 1, bf1); BAR8();                                        \
        LDA8(aBO, 1); STG8B(49152, 0, k3);                                     \
        BAR8(); MM8(1, 1, bf1); BAR8();                                        \
        STG8B(49152, 1, k3);                                                   \
        BAR8(); MM8(1, 0, bf0); VM4(); BAR8();                                 \
    }

// ---------------------------------------------------------------------------
// gemm1_8: h1 = relu(deep_x @ W1b^T + b1), K=256 (zero-padded).
// A-staging sources: k-tiles 0..2 gather from emb_bf16 [f][256][64] (row via
// packed sp scalar PKh_j, selected by (kt>>6)*8 bit shift -- pure ALU, no
// runtime-indexed arrays); k-tile 3 reads dtail [B][64]. B rows staged
// permuted (prow = 4*(t&15) + (t>>4)) so lane lam's acc cols jn map to
// n = bn + wn*64 + 4*lam + jn -> natural-layout u16x4 packed stores.
// ---------------------------------------------------------------------------
#define ASRC1(pkv, h2, kt) ((kt) < 192                                         \
    ? (embb + (((kt) >> 6) << 14)                                              \
            + ((int)(((pkv) >> (((kt) >> 6) << 3)) & 255u) << 6) + csel)       \
    : (dtail + (size_t)(b0 + (h2) * 64) * 64 + csel))

#define STG8A(regoff, h, kt) do {                                              \
    async_ld16(ASRC1(PK##h##_0, 2*(h), kt),                                    \
               &lds[(regoff) + (h) * 8192 + wave * 512]);                      \
    async_ld16(ASRC1(PK##h##_1, 2*(h)+1, kt),                                  \
               &lds[(regoff) + (h) * 8192 + 4096 + wave * 512]);               \
} while (0)

#define STG8B(regoff, h, kt) do {                                              \
    const uint16_t* g_ = bRow + (size_t)((h) * 128) * (size_t)K + (kt);        \
    async_ld16(g_, &lds[(regoff) + (h) * 8192 + wave * 512]);                  \
    async_ld16(g_ + (size_t)64 * (size_t)K,                                    \
               &lds[(regoff) + (h) * 8192 + 4096 + wave * 512]);               \
} while (0)

__global__ __launch_bounds__(512, 2) void gemm1_8(
    const int* __restrict__ sp, const uint16_t* __restrict__ embb,
    const uint16_t* __restrict__ dtail, const uint16_t* __restrict__ Bw,
    const float* __restrict__ bias, uint16_t* __restrict__ C)
{
    __shared__ __align__(16) uint16_t lds[65536];   // 128 KiB
    GEMM8_DECLS()
    const int K = K1;
    const int b0 = bm + trow;
    // pack sparse ids for the 4 A-row slots (rows b0 + {0,64,128,192})
    const uint32_t PK0_0 = (uint32_t)sp[(b0      ) * 3] |
                           ((uint32_t)sp[(b0      ) * 3 + 1] << 8) |
                           ((uint32_t)sp[(b0      ) * 3 + 2] << 16);
    const uint32_t PK0_1 = (uint32_t)sp[(b0 +  64) * 3] |
                           ((uint32_t)sp[(b0 +  64) * 3 + 1] << 8) |
                           ((uint32_t)sp[(b0 +  64) * 3 + 2] << 16);
    const uint32_t PK1_0 = (uint32_t)sp[(b0 + 128) * 3] |
                           ((uint32_t)sp[(b0 + 128) * 3 + 1] << 8) |
                           ((uint32_t)sp[(b0 + 128) * 3 + 2] << 16);
    const uint32_t PK1_1 = (uint32_t)sp[(b0 + 192) * 3] |
                           ((uint32_t)sp[(b0 + 192) * 3 + 1] << 8) |
                           ((uint32_t)sp[(b0 + 192) * 3 + 2] << 16);
    const int prow = 4 * (trow & 15) + (trow >> 4);
    const uint16_t* bRow = Bw + (size_t)(bn + prow) * K + csel;
    VM0();   // drain sp loads: counted-vmcnt FIFO must start clean
    GEMM8_MAIN()

    float bv[4];
#pragma unroll
    for (int jn = 0; jn < 4; jn++) bv[jn] = bias[bn + wn * 64 + 4 * lam + jn];
#pragma unroll
    for (int im = 0; im < 8; im++) {
#pragma unroll
        for (int r = 0; r < 4; r++) {
            int m = bm + wm * 128 + im * 16 + lad * 4 + r;
            u16x4 o;
#pragma unroll
            for (int jn = 0; jn < 4; jn++)
                o[jn] = f2bf(fmaxf(acc[im][jn][r] + bv[jn], 0.f));
            *(u16x4*)&C[(size_t)m * HDIM + bn + wn * 64 + 4 * lam] = o;
        }
    }
}

#undef STG8A
#undef STG8B

// ---------------------------------------------------------------------------
// gemm_fused8: relu(acc + b2) . W3 partials -> LDS wn-reduce -> one
// atomicAdd per row per block. Last-arriving of the 4 bx sharers (per-strip
// counter; adds retired via vmcnt(0) before increment) atomic-reads the 256
// finished logits and writes sigmoid(out). No fences.
// ---------------------------------------------------------------------------
#define STG8A(regoff, h, kt) do {                                              \
    const uint16_t* g_ = aRow + (size_t)((h) * 128) * (size_t)K + (kt);        \
    async_ld16(g_, &lds[(regoff) + (h) * 8192 + wave * 512]);                  \
    async_ld16(g_ + (size_t)64 * (size_t)K,                                    \
               &lds[(regoff) + (h) * 8192 + 4096 + wave * 512]);               \
} while (0)

#define STG8B(regoff, h, kt) do {                                              \
    const uint16_t* g_ = bRow + (size_t)((h) * 128) * (size_t)K + (kt);        \
    async_ld16(g_, &lds[(regoff) + (h) * 8192 + wave * 512]);                  \
    async_ld16(g_ + (size_t)64 * (size_t)K,                                    \
               &lds[(regoff) + (h) * 8192 + 4096 + wave * 512]);               \
} while (0)

__global__ __launch_bounds__(512, 2) void gemm_fused8(
    const uint16_t* __restrict__ A, const uint16_t* __restrict__ Bw,
    const float* __restrict__ bias, const float* __restrict__ W3,
    float* __restrict__ outacc, int* __restrict__ cnt,
    float* __restrict__ out, int M, int N, int K)
{
    __shared__ __align__(16) uint16_t lds[65536];   // 128 KiB
    __shared__ int doneFlag;
    GEMM8_DECLS()
    const uint16_t* aRow = A + (size_t)(bm + trow) * K + csel;
    const uint16_t* bRow = Bw + (size_t)(bn + trow) * K + csel;
    GEMM8_MAIN()

    float bv[4], w3v[4];
#pragma unroll
    for (int jn = 0; jn < 4; jn++) {
        int n = bn + wn * 64 + jn * 16 + lam;
        bv[jn] = bias[n];
        w3v[jn] = W3[n];
    }
    // ---- stage per-wave row partials into (now dead) GEMM LDS ----
    float* ldsF = (float*)lds;             // [4 wn][256 rows]
    __syncthreads();                       // all LDS reads of GEMM done
#pragma unroll
    for (int im = 0; im < 8; im++) {
#pragma unroll
        for (int r = 0; r < 4; r++) {
            float pt = 0.f;
#pragma unroll
            for (int jn = 0; jn < 4; jn++)
                pt += fmaxf(acc[im][jn][r] + bv[jn], 0.f) * w3v[jn];
            pt += __shfl_xor(pt, 1);
            pt += __shfl_xor(pt, 2);
            pt += __shfl_xor(pt, 4);
            pt += __shfl_xor(pt, 8);
            if (lam == 0)
                ldsF[wn * 256 + wm * 128 + im * 16 + lad * 4 + r] = pt;
        }
    }
    __syncthreads();
    if (tid < 256) {                       // one atomic per row per block
        float s = (ldsF[tid] + ldsF[256 + tid])
                + (ldsF[512 + tid] + ldsF[768 + tid]);
        atomicAdd(&outacc[bm + tid], s);
    }
    VM0();                                 // adds retired at coherent point
    __syncthreads();
    if (tid == 0) doneFlag = atomicAdd(&cnt[by], 1);
    __syncthreads();
    if (doneFlag == 3 && tid < 256) {      // last sharer: finish the strip
        float v = atomicAdd(&outacc[bm + tid], 0.f);   // coherent read
        out[bm + tid] = 1.f / (1.f + __expf(-v));
    }
}

#undef STG8A
#undef STG8B

// ---------------------------------------------------------------------------
extern "C" void kernel_launch(void* const* d_in, const int* in_sizes, int n_in,
                              void* d_out, int out_size, void* d_ws, size_t ws_size,
                              hipStream_t stream) {
    const int*   sp    = (const int*)d_in[0];
    const float* dense = (const float*)d_in[1];
    const float* ww    = (const float*)d_in[2];
    const float* wb    = (const float*)d_in[3];
    const float* emb   = (const float*)d_in[4];
    const float* W1    = (const float*)d_in[5];
    const float* b1    = (const float*)d_in[6];
    const float* W2    = (const float*)d_in[7];
    const float* b2    = (const float*)d_in[8];
    const float* W3    = (const float*)d_in[9];
    const float* b3    = (const float*)d_in[10];
    float* out = (float*)d_out;

    char* ws = (char*)d_ws;
    float*    wide  = (float*)ws;                      //     65,536 B
    uint16_t* embb  = (uint16_t*)(ws + 65536);         //     98,304 B (3x256x64)
    uint16_t* dtail = (uint16_t*)(ws + 163840);        //  2,097,152 B (16384x64)
    uint16_t* W1b   = (uint16_t*)(ws + 2260992);       //    524,288 B (1024x256)
    uint16_t* W2b   = (uint16_t*)(ws + 2785280);       //  2,097,152 B
    uint16_t* h1    = (uint16_t*)(ws + 4882432);       // 33,554,432 B
    int*      cnt   = (int*)(ws + 38436864);           //        256 B -> 38,437,120

    prep_kernel<<<1241, 256, 0, stream>>>(
        sp, dense, emb, W1, W2, ww, wb, b3, embb, dtail, W1b, W2b, wide, cnt);
    gemm1_8<<<256, 512, 0, stream>>>(
        sp, embb, dtail, W1b, b1, h1);
    gemm_fused8<<<256, 512, 0, stream>>>(
        h1, W2b, b2, W3, wide, cnt, out, BATCH, HDIM, HDIM);
}

// Round 6
// 160.579 us; speedup vs baseline: 1.0014x; 1.0014x over previous
//
#include <hip/hip_runtime.h>
#include <stdint.h>

// ---------------------------------------------------------------------------
// WideAndDeep: B=16384, F=3, C=256, D=64, H=1024, ND=13
// R20: GEMM core rebuilt as a 4-deep K-tile ring (BK=32) to fix the
// diagnosed stall (R19 counters: gemm2 42us, MfmaUtil 31%, HBM 8% ->
// latency-bound; old dbuf gave only 2-3 phases of vmcnt lead vs 200-900cy
// load latency). Ring-4: while computing tile t, stage tile t+3 into the
// slot tile t-1 vacated; vmcnt(8) once per tile waits for loads issued
// 4-5 phases (~620-775cy) earlier. Phase pacing is UNCHANGED from the
// proven schedule: per phase {ds-reads | 2 staging loads | BAR | 16 MFMA
// | BAR}, 4 barriers + 32 MFMA + 4 loads per 32-K tile = same rates as
// the R16 8-phase/BK=64 structure. LDS 128KiB: A slots s*8192, B slots
// 32768+s*8192 (s=0..3), each [256 rows][32 K] with group-XOR swizzle
// g' = g ^ ((row>>1)&3) (read kce is lane-constant; source pre-swizzled;
// dest linear). Epilogues/sigmoid reverted to R18's proven forms.
// WAR proof: slot (t+3)&3 holds tile t-1, whose last ds_read completed
// behind >=2 barriers before the stage issues; tiles t..t+3 occupy 4
// distinct slots. FIFO proof (per wave): prologue stages A0,B0..A2,B2
// (12 loads), vmcnt(8) retires A0,B0; tile t stages A(t+3)@pA, B(t+3)@pB,
// vmcnt(8)@pB-end retires A(t+1),B(t+1) (issued (t-2).pA/pB = 5/4 phases
// earlier). Tail stages wrap to kt=0 (dead, slot never re-read).
// ---------------------------------------------------------------------------

#define BATCH 16384
#define HDIM 1024
#define K1 256
#define DEEP_IN 205

typedef short bf16x8 __attribute__((ext_vector_type(8)));
typedef float f32x4 __attribute__((ext_vector_type(4)));
typedef uint16_t u16x8 __attribute__((ext_vector_type(8)));
typedef uint16_t u16x4 __attribute__((ext_vector_type(4)));

__device__ __forceinline__ uint16_t f2bf(float f) {
    uint32_t x;
    __builtin_memcpy(&x, &f, 4);
    uint32_t r = (x + 0x7fffu + ((x >> 16) & 1u)) >> 16;
    return (uint16_t)r;
}

__device__ __forceinline__ void async_ld16(const uint16_t* g, uint16_t* l) {
    __builtin_amdgcn_global_load_lds(
        (const __attribute__((address_space(1))) uint32_t*)g,
        (__attribute__((address_space(3))) uint32_t*)l, 16, 0, 0);
}

// ---------------------------------------------------------------------------
// prep: everything the GEMMs need, one elementwise kernel (R18 form).
//   [0, 24)      : emb -> emb_bf16 (49152 elems, x8)
//   [24, 536)    : dtail [B][64] bf16: cols 0..12 = dense, 13..63 = 0 (x8)
//   [536, 664)   : W1 -> bf16, 205 -> 256 K-pad (x8)
//   [664, 1176)  : W2 -> bf16 (x8)
//   [1176, 1240) : wide path (sparse gathers + dense dot) + b3 seed
// ---------------------------------------------------------------------------
__global__ __launch_bounds__(256) void prep_kernel(
    const int* __restrict__ sp, const float* __restrict__ dense,
    const float* __restrict__ emb, const float* __restrict__ W1,
    const float* __restrict__ W2, const float* __restrict__ ww,
    const float* __restrict__ wb, const float* __restrict__ b3,
    uint16_t* __restrict__ embb, uint16_t* __restrict__ dtail,
    uint16_t* __restrict__ W1b, uint16_t* __restrict__ W2b,
    float* __restrict__ wide)
{
    const int bid = blockIdx.x;
    const int tid = threadIdx.x;
    if (bid < 24) {                        // ---- emb -> bf16 (3*256*64 = 49152)
        int k = bid * 256 + tid;           // < 6144 vec8
        const float* src = emb + (size_t)k * 8;
        float4 v0 = *(const float4*)src;
        float4 v1 = *(const float4*)(src + 4);
        u16x8 o;
        o[0] = f2bf(v0.x); o[1] = f2bf(v0.y); o[2] = f2bf(v0.z); o[3] = f2bf(v0.w);
        o[4] = f2bf(v1.x); o[5] = f2bf(v1.y); o[6] = f2bf(v1.z); o[7] = f2bf(v1.w);
        *(u16x8*)(embb + (size_t)k * 8) = o;
    } else if (bid < 536) {                // ---- dense tail [16384][64]
        int idx = (bid - 24) * 256 + tid;  // < 131072 vec8
        int b = idx >> 3, c0 = (idx & 7) * 8;
        u16x8 o;
#pragma unroll
        for (int t = 0; t < 8; t++) {
            int c = c0 + t;
            o[t] = (c < 13) ? f2bf(dense[b * 13 + c]) : (uint16_t)0;
        }
        *(u16x8*)(dtail + (size_t)b * 64 + c0) = o;
    } else if (bid < 664) {                // ---- W1 convert, 205 -> 256
        int idx = (bid - 536) * 256 + tid;     // < 32768
        int n = idx >> 5, c0 = (idx & 31) * 8;
        u16x8 o;
#pragma unroll
        for (int t = 0; t < 8; t++) {
            int c = c0 + t;
            o[t] = (c < DEEP_IN) ? f2bf(W1[n * DEEP_IN + c]) : (uint16_t)0;
        }
        *(u16x8*)(W1b + (size_t)n * K1 + c0) = o;
    } else if (bid < 1176) {               // ---- W2 convert (x8)
        int k = (bid - 664) * 256 + tid;       // < 131072
        const float* src = W2 + (size_t)k * 8;
        float4 v0 = *(const float4*)src;
        float4 v1 = *(const float4*)(src + 4);
        u16x8 o;
        o[0] = f2bf(v0.x); o[1] = f2bf(v0.y); o[2] = f2bf(v0.z); o[3] = f2bf(v0.w);
        o[4] = f2bf(v1.x); o[5] = f2bf(v1.y); o[6] = f2bf(v1.z); o[7] = f2bf(v1.w);
        *(u16x8*)(W2b + (size_t)k * 8) = o;
    } else {                               // ---- wide path (+ b3 seed)
        int b = (bid - 1176) * 256 + tid;      // < 16384
        int s0 = sp[b * 3], s1 = sp[b * 3 + 1], s2 = sp[b * 3 + 2];
        float w = wb[0] + b3[0];
        w += ww[s0] + ww[256 + s1] + ww[512 + s2];
        w += ww[768    + s0 * 3 + s1];
        w += ww[66304  + s0 * 3 + s2];
        w += ww[131840 + s1 * 3 + s2];
        w += ww[197376 + (s0 * 3 + s1) * 3 + s2];
        const float* wd = ww + 16974592;
        float acc2 = 0.f;
#pragma unroll
        for (int j = 0; j < 13; j++) acc2 += dense[b * 13 + j] * wd[j];
        wide[b] = w + acc2;
    }
}

// ---------------------------------------------------------------------------
// Ring-4 GEMM core. 256x256 tile, 8 waves 2m x 4n, wave tile 128x64, BK=32.
// Per tile t: pA {LDA(msub0) 4 + LDB 4 ds_reads; stage A(t+3); BAR; 16 MFMA;
// BAR}; pB {LDA(msub1) 4; stage B(t+3); BAR; 16 MFMA; vmcnt(8); BAR}.
// ---------------------------------------------------------------------------
#define BAR8() do { asm volatile("" ::: "memory");                             \
    __builtin_amdgcn_s_barrier();                                              \
    asm volatile("" ::: "memory"); } while (0)
#define VM8() asm volatile("s_waitcnt vmcnt(8)" ::: "memory")
#define VM0() asm volatile("s_waitcnt vmcnt(0)" ::: "memory")

#define LDA4(sA, msub) do {                                                    \
    _Pragma("unroll") for (int mt = 0; mt < 4; mt++)                           \
        af[mt] = *(const bf16x8*)&lds[(sA) * 8192 + aOff                       \
                                      + ((msub) * 64 + mt * 16) * 32];         \
} while (0)

#define LDB4(sB) do {                                                          \
    _Pragma("unroll") for (int nt = 0; nt < 4; nt++)                           \
        bf[nt] = *(const bf16x8*)&lds[32768 + (sB) * 8192 + bOff + nt * 512];  \
} while (0)

#define MM4(msub) do {                                                         \
    __builtin_amdgcn_s_setprio(1);                                             \
    _Pragma("unroll") for (int mt = 0; mt < 4; mt++)                           \
    _Pragma("unroll") for (int nt = 0; nt < 4; nt++)                           \
        acc[(msub) * 4 + mt][nt] = __builtin_amdgcn_mfma_f32_16x16x32_bf16(    \
            af[mt], bf[nt], acc[(msub) * 4 + mt][nt], 0, 0, 0);                \
    __builtin_amdgcn_s_setprio(0); } while (0)

#define GEMM4_DECLS()                                                          \
    const int tid = threadIdx.x;                                               \
    const int lane = tid & 63, wave = tid >> 6;                                \
    const int wm = wave >> 2, wn = wave & 3;                                   \
    const int id = blockIdx.x;                                                 \
    const int wg = (id & 7) * 32 + (id >> 3);                                  \
    const int by = wg >> 2, bx = wg & 3;                                       \
    const int bm = by * 256, bn = bx * 256;                                    \
    const int lam = lane & 15, lad = lane >> 4;                                \
    const int kce = (lad ^ ((lam >> 1) & 3)) * 8;   /* read swizzle (elems) */ \
    const int aOff = (wm * 128 + lam) * 32 + kce;                              \
    const int bOff = (wn * 64 + lam) * 32 + kce;                               \
    const int trow = tid >> 2;                       /* 0..127 */              \
    const int gsrc = ((tid & 3) ^ ((tid >> 3) & 3)) * 8;  /* src pre-swz */

// Main: prologue stages tiles 0..2; loop stages t+3 (kt wraps dead for
// t+3 >= NT); vmcnt(8) once per tile at pB end.
#define GEMM4_MAIN(STA, STB)                                                   \
    f32x4 acc[8][4];                                                           \
    _Pragma("unroll") for (int i = 0; i < 8; i++)                              \
        _Pragma("unroll") for (int j = 0; j < 4; j++) acc[i][j] = (f32x4)0.f;  \
    bf16x8 af[4], bf[4];                                                       \
    const int NT = K >> 5;                                                     \
    STA(0, 0);  STB(0, 0);                                                     \
    STA(1, 32); STB(1, 32);                                                    \
    STA(2, 64); STB(2, 64);                                                    \
    VM8();                                                                     \
    BAR8();                                                                    \
    for (int t = 0; t < NT; ++t) {                                             \
        const int s = t & 3, s3 = (t + 3) & 3;                                 \
        const int kt3 = (t + 3 < NT ? t + 3 : 0) << 5;                         \
        LDA4(s, 0); LDB4(s); STA(s3, kt3);                                     \
        BAR8(); MM4(0); BAR8();                                                \
        LDA4(s, 1); STB(s3, kt3);                                              \
        BAR8(); MM4(1); VM8(); BAR8();                                         \
    }

// ---------------------------------------------------------------------------
// gemm1_8: h1 = relu(deep_x @ W1b^T + b1), K=256 (zero-padded).
// A staging gathers from L2-resident emb_bf16 (fields = 2 tiles each) and
// dtail (tiles 6,7); per-thread packed sp scalars, field via (kt>>6)*8
// shift. B rows staged permuted n(r) = bn + (r&192) + 4*(r&15) + ((r>>4)&3)
// so lane lam's acc cols jn map to n = bn+wn*64+4*lam+jn -> u16x4 stores.
// ---------------------------------------------------------------------------
#define ASRC1(pk, b, kt) ((kt) < 192                                           \
    ? (embb + (((kt) >> 6) << 14)                                              \
            + ((int)(((pk) >> (((kt) >> 6) << 3)) & 255u) << 6)                \
            + ((kt) & 63) + gsrc)                                              \
    : (dtail + (size_t)(b) * 64 + ((kt) - 192) + gsrc))

#define STGA1(s, kt) do {                                                      \
    async_ld16(ASRC1(PKa, b1, kt), &lds[(s) * 8192 + wave * 512]);             \
    async_ld16(ASRC1(PKb, b2, kt), &lds[(s) * 8192 + 4096 + wave * 512]);      \
} while (0)

#define STGB1(s, kt) do {                                                      \
    async_ld16(bR1 + (kt), &lds[32768 + (s) * 8192 + wave * 512]);             \
    async_ld16(bR2 + (kt), &lds[32768 + (s) * 8192 + 4096 + wave * 512]);      \
} while (0)

__global__ __launch_bounds__(512, 2) void gemm1_8(
    const int* __restrict__ sp, const uint16_t* __restrict__ embb,
    const uint16_t* __restrict__ dtail, const uint16_t* __restrict__ Bw,
    const float* __restrict__ bias, uint16_t* __restrict__ C)
{
    __shared__ __align__(16) uint16_t lds[65536];   // 128 KiB
    GEMM4_DECLS()
    const int K = K1;
    const int b1 = bm + trow, b2 = bm + 128 + trow;
    const uint32_t PKa = (uint32_t)sp[b1 * 3] |
                         ((uint32_t)sp[b1 * 3 + 1] << 8) |
                         ((uint32_t)sp[b1 * 3 + 2] << 16);
    const uint32_t PKb = (uint32_t)sp[b2 * 3] |
                         ((uint32_t)sp[b2 * 3 + 1] << 8) |
                         ((uint32_t)sp[b2 * 3 + 2] << 16);
    const int n1 = bn + (trow & 192) + 4 * (trow & 15) + ((trow >> 4) & 3);
    const int r2v = 128 + trow;
    const int n2 = bn + (r2v & 192) + 4 * (trow & 15) + ((trow >> 4) & 3);
    const uint16_t* bR1 = Bw + (size_t)n1 * K + gsrc;
    const uint16_t* bR2 = Bw + (size_t)n2 * K + gsrc;
    VM0();   // drain sp loads: counted-vmcnt FIFO must start clean
    GEMM4_MAIN(STGA1, STGB1)

    float bv[4];
#pragma unroll
    for (int jn = 0; jn < 4; jn++) bv[jn] = bias[bn + wn * 64 + 4 * lam + jn];
#pragma unroll
    for (int im = 0; im < 8; im++) {
#pragma unroll
        for (int r = 0; r < 4; r++) {
            int m = bm + wm * 128 + im * 16 + lad * 4 + r;
            u16x4 o;
#pragma unroll
            for (int jn = 0; jn < 4; jn++)
                o[jn] = f2bf(fmaxf(acc[im][jn][r] + bv[jn], 0.f));
            *(u16x4*)&C[(size_t)m * HDIM + bn + wn * 64 + 4 * lam] = o;
        }
    }
}

#undef STGA1
#undef STGB1

// ---------------------------------------------------------------------------
// gemm_fused8: per-row partial of relu(acc + b2) . W3 -> atomicAdd(outacc).
// (Natural B staging; n-permutation irrelevant to the reduction.)
// ---------------------------------------------------------------------------
#define STGA2(s, kt) do {                                                      \
    async_ld16(aR1 + (kt), &lds[(s) * 8192 + wave * 512]);                     \
    async_ld16(aR2 + (kt), &lds[(s) * 8192 + 4096 + wave * 512]);              \
} while (0)

#define STGB2(s, kt) do {                                                      \
    async_ld16(bR1 + (kt), &lds[32768 + (s) * 8192 + wave * 512]);             \
    async_ld16(bR2 + (kt), &lds[32768 + (s) * 8192 + 4096 + wave * 512]);      \
} while (0)

__global__ __launch_bounds__(512, 2) void gemm_fused8(
    const uint16_t* __restrict__ A, const uint16_t* __restrict__ Bw,
    const float* __restrict__ bias, const float* __restrict__ W3,
    float* __restrict__ outacc, int M, int N, int K)
{
    __shared__ __align__(16) uint16_t lds[65536];   // 128 KiB
    GEMM4_DECLS()
    const uint16_t* aR1 = A + (size_t)(bm + trow) * K + gsrc;
    const uint16_t* aR2 = A + (size_t)(bm + 128 + trow) * K + gsrc;
    const uint16_t* bR1 = Bw + (size_t)(bn + trow) * K + gsrc;
    const uint16_t* bR2 = Bw + (size_t)(bn + 128 + trow) * K + gsrc;
    GEMM4_MAIN(STGA2, STGB2)

    float bv[4], w3v[4];
#pragma unroll
    for (int jn = 0; jn < 4; jn++) {
        int n = bn + wn * 64 + jn * 16 + lam;
        bv[jn] = bias[n];
        w3v[jn] = W3[n];
    }
#pragma unroll
    for (int im = 0; im < 8; im++) {
#pragma unroll
        for (int r = 0; r < 4; r++) {
            float pt = 0.f;
#pragma unroll
            for (int jn = 0; jn < 4; jn++)
                pt += fmaxf(acc[im][jn][r] + bv[jn], 0.f) * w3v[jn];
            pt += __shfl_xor(pt, 1);
            pt += __shfl_xor(pt, 2);
            pt += __shfl_xor(pt, 4);
            pt += __shfl_xor(pt, 8);
            if (lam == 0) {
                int m = bm + wm * 128 + im * 16 + lad * 4 + r;
                atomicAdd(&outacc[m], pt);
            }
        }
    }
}

#undef STGA2
#undef STGB2

// ---------------------------------------------------------------------------
// Sigmoid over the accumulated logits. Grid 64 x 256.
// ---------------------------------------------------------------------------
__global__ __launch_bounds__(256) void sigmoid_kernel(
    const float* __restrict__ outacc, float* __restrict__ out)
{
    int b = blockIdx.x * 256 + threadIdx.x;
    out[b] = 1.f / (1.f + __expf(-outacc[b]));
}

// ---------------------------------------------------------------------------
extern "C" void kernel_launch(void* const* d_in, const int* in_sizes, int n_in,
                              void* d_out, int out_size, void* d_ws, size_t ws_size,
                              hipStream_t stream) {
    const int*   sp    = (const int*)d_in[0];
    const float* dense = (const float*)d_in[1];
    const float* ww    = (const float*)d_in[2];
    const float* wb    = (const float*)d_in[3];
    const float* emb   = (const float*)d_in[4];
    const float* W1    = (const float*)d_in[5];
    const float* b1    = (const float*)d_in[6];
    const float* W2    = (const float*)d_in[7];
    const float* b2    = (const float*)d_in[8];
    const float* W3    = (const float*)d_in[9];
    const float* b3    = (const float*)d_in[10];
    float* out = (float*)d_out;

    char* ws = (char*)d_ws;
    float*    wide  = (float*)ws;                      //     65,536 B
    uint16_t* embb  = (uint16_t*)(ws + 65536);         //     98,304 B (3x256x64)
    uint16_t* dtail = (uint16_t*)(ws + 163840);        //  2,097,152 B (16384x64)
    uint16_t* W1b   = (uint16_t*)(ws + 2260992);       //    524,288 B (1024x256)
    uint16_t* W2b   = (uint16_t*)(ws + 2785280);       //  2,097,152 B
    uint16_t* h1    = (uint16_t*)(ws + 4882432);       // 33,554,432 B -> 38,436,864 total

    prep_kernel<<<1240, 256, 0, stream>>>(
        sp, dense, emb, W1, W2, ww, wb, b3, embb, dtail, W1b, W2b, wide);
    gemm1_8<<<256, 512, 0, stream>>>(
        sp, embb, dtail, W1b, b1, h1);
    gemm_fused8<<<256, 512, 0, stream>>>(
        h1, W2b, b2, W3, wide, BATCH, HDIM, HDIM);
    sigmoid_kernel<<<BATCH / 256, 256, 0, stream>>>(wide, out);
}